// Round 10
// baseline (279.286 us; speedup 1.0000x reference)
//
#include <hip/hip_runtime.h>
#include <cstdint>
#include <cstddef>

typedef unsigned long long u64;
typedef unsigned int u32;

#define SLICES 2
#define SCAND 192           // per-slice pool capacity
#define CAND 384            // SLICES * SCAND
#define NSLOT 6             // CAND / 64
#define NBINS 4096
#define SEL_THR 1024
#define SEL_TARGET 128
#define POOLCAP 4096
#define MASKW 3200          // 102400 columns max as bits
#define TOP8 8

// IoU exactly as reference _box_iou, all f32 IEEE ops (bit-exact, absmax=0 rounds 1-9).
__device__ __forceinline__ float iou_f32(float4 p, float4 t, float area_t) {
  float area1 = (p.z - p.x) * (p.w - p.y);
  float ltx = fmaxf(p.x, t.x);
  float lty = fmaxf(p.y, t.y);
  float rbx = fminf(p.z, t.z);
  float rby = fminf(p.w, t.w);
  float wx = fmaxf(rbx - ltx, 0.0f);
  float wy = fmaxf(rby - lty, 0.0f);
  float inter = wx * wy;
  return inter / (area1 + area_t - inter);
}

__device__ __forceinline__ u64 map_cost(double cur) {
  u64 b = (u64)__double_as_longlong(cur);
  if (b == 0x8000000000000000ull) b = 0;                 // canonicalize -0 -> +0
  return (b >> 63) ? ~b : (b | 0x8000000000000000ull);   // order-exact total map
}
__device__ __forceinline__ double unmap_cost(u64 m) {
  u64 b = (m >> 63) ? (m ^ 0x8000000000000000ull) : ~m;
  return __longlong_as_double((long long)b);
}

// Key encoding: (io_bits << 32) | (0xFFFFFFFF - col). Raw u64 max = (io desc, col asc).

// Kernel A: unchanged (proven absmax=0 rounds 8-9).
__global__ __launch_bounds__(SEL_THR) void select_kernel(const float4* __restrict__ pbox,
                                                         const float4* __restrict__ tbox,
                                                         u64* __restrict__ ckey,
                                                         int M, int NROWS) {
  __shared__ u32 s_hist[NBINS];
  __shared__ int s_csum[SEL_THR];
  __shared__ u64 s_pool[POOLCAP];
  __shared__ int s_n, s_n2, s_B;
  const int tid = threadIdx.x;
  const int lane = tid & 63;
  const int slice = blockIdx.x, row = blockIdx.y;
  const int sw = (M + SLICES - 1) / SLICES;
  const int base = slice * sw;
  const int send = min(base + sw, M);
  const float4 tb = tbox[row];
  const float area_t = (tb.z - tb.x) * (tb.w - tb.y);
  u64* orow_key = ckey + (size_t)row * CAND + slice * SCAND;

  for (int b = tid; b < NBINS; b += SEL_THR) s_hist[b] = 0;
  if (tid == 0) { s_n = 0; s_n2 = 0; s_B = 0; }
  __syncthreads();

  const u64 lowmask = (1ull << lane) - 1ull;
  const int iters = (sw + SEL_THR - 1) / SEL_THR;
  for (int it = 0; it < iters; ++it) {
    int j = base + it * SEL_THR + tid;
    bool inr = (j < send);
    float io = -1.0f;
    if (inr) io = iou_f32(pbox[j], tb, area_t);
    bool pos = inr && (io > 0.0f);
    u64 pm = __ballot(pos);
    int wn = (int)__popcll(pm);
    if (wn) {
      int wb = 0;
      if (lane == 0) wb = atomicAdd(&s_n, wn);
      wb = __shfl(wb, 0);
      if (pos) {
        int idx = wb + (int)__popcll(pm & lowmask);
        if (idx < POOLCAP) s_pool[idx] = ((u64)__float_as_uint(io) << 32) | (u64)(0xFFFFFFFFu - (u32)j);
        atomicAdd(&s_hist[__float_as_uint(io) >> 18], 1u);
      }
    }
  }
  __syncthreads();
  const int np = s_n;

  {
    int b0 = tid * 4;
    s_csum[tid] = (int)(s_hist[b0] + s_hist[b0 + 1] + s_hist[b0 + 2] + s_hist[b0 + 3]);
  }
  __syncthreads();

  if (tid < 64) {
    if (np >= SEL_TARGET) {
      int R = 0; bool found = false;
      for (int ch = SEL_THR / 64 - 1; ch >= 0 && !found; --ch) {
        int cum = s_csum[ch * 64 + tid];
        for (int off = 1; off < 64; off <<= 1) {
          int o = __shfl_down(cum, off);
          if (tid + off < 64) cum += o;
        }
        int chunksum = __shfl(cum, 0);
        if (R + chunksum >= SEL_TARGET) {
          u64 m = __ballot(R + cum >= SEL_TARGET);
          int l = 63 - __clzll(m);
          int R2 = R + ((l < 63) ? __shfl(cum, l + 1) : 0);
          if (tid == 0) {
            int bb = (ch * 64 + l) * 4;
            int B2 = bb;
            for (int b = bb + 3; b >= bb; --b) {
              R2 += (int)s_hist[b];
              if (R2 >= SEL_TARGET) { B2 = b; break; }
            }
            s_B = B2;
          }
          found = true;
        } else R += chunksum;
      }
    }
  }
  __syncthreads();
  const int B = s_B;

  if (np >= SEL_TARGET) {
    if (np <= POOLCAP) {
      for (int t = tid; t < np; t += SEL_THR) {
        u64 k = s_pool[t];
        if ((u32)(k >> 50) >= (u32)B) {
          int pos = atomicAdd(&s_n2, 1);
          if (pos < SCAND) orow_key[pos] = k;
        }
      }
    } else {
      for (int j = base + tid; j < send; j += SEL_THR) {
        float io = iou_f32(pbox[j], tb, area_t);
        if (io > 0.0f && (int)(__float_as_uint(io) >> 18) >= B) {
          int pos = atomicAdd(&s_n2, 1);
          if (pos < SCAND) orow_key[pos] = ((u64)__float_as_uint(io) << 32) | (u64)(0xFFFFFFFFu - (u32)j);
        }
      }
    }
    __syncthreads();
  } else {
    for (int t = tid; t < np; t += SEL_THR) {
      u64 k = s_pool[t];
      int pos = atomicAdd(&s_n2, 1);
      if (pos < SCAND) orow_key[pos] = k;
    }
    __syncthreads();
    if (tid < 64) {
      int need = SEL_TARGET - np, got = 0;
      int base_n = s_n2;
      for (int b2 = base; b2 < send && got < need; b2 += 64) {
        int j = b2 + tid;
        float io = (j < send) ? iou_f32(pbox[j], tb, area_t) : -1.0f;
        bool z = (j < send) && (io == 0.0f);
        u64 zm = __ballot(z);
        int rank = (int)__popcll(zm & ((1ull << tid) - 1ull));
        if (z && rank < need - got) {
          int pos = base_n + got + rank;
          if (pos < SCAND) orow_key[pos] = (u64)(0xFFFFFFFFu - (u32)j);
        }
        int zn = (int)__popcll(zm); if (zn > need - got) zn = need - got;
        got += zn;
      }
      if (tid == 0) s_n2 = base_n + got;
    }
    __syncthreads();
  }
  int n = min(s_n2, SCAND);
  for (int t2 = n + tid; t2 < SCAND; t2 += SEL_THR) orow_key[t2] = 0ull;
}

// owned-min DPP reduce step (identity: key=~0, col=INT_MAX); result lands lane 63
#define DPP_STEP(CTRL) do { \
  u32 ohi = (u32)__builtin_amdgcn_update_dpp((int)0xFFFFFFFF, (int)khi, (CTRL), 0xF, 0xF, false); \
  u32 olo = (u32)__builtin_amdgcn_update_dpp((int)0xFFFFFFFF, (int)klo, (CTRL), 0xF, 0xF, false); \
  int ocl =      __builtin_amdgcn_update_dpp((int)0x7FFFFFFF, kcol,     (CTRL), 0xF, 0xF, false); \
  bool lt = (ohi < khi) || (ohi == khi && ((olo < klo) || (olo == klo && ocl < kcol))); \
  if (lt) { khi = ohi; klo = olo; kcol = ocl; } \
} while (0)

// max DPP step (identity: 0)
#define DPPMAX(CTRL) do { \
  u32 oh2 = (u32)__builtin_amdgcn_update_dpp(0, (int)mhi, (CTRL), 0xF, 0xF, false); \
  u32 ol2 = (u32)__builtin_amdgcn_update_dpp(0, (int)mlo, (CTRL), 0xF, 0xF, false); \
  bool gt = (oh2 > mhi) || (oh2 == mhi && ol2 > mlo); \
  if (gt) { mhi = oh2; mlo = ol2; } \
} while (0)

// Kernel A2: exact top-8 of each row's pool by u64 key (unchanged, proven).
__global__ __launch_bounds__(64) void top8_kernel(const u64* __restrict__ ckey,
                                                  u64* __restrict__ top8g, int NROWS) {
  const int lane = threadIdx.x;
  const int row = blockIdx.x;
  const u64* kp = ckey + (size_t)row * CAND;
  u64 k[NSLOT];
#pragma unroll
  for (int s = 0; s < NSLOT; ++s) k[s] = kp[(s << 6) + lane];
  u64 out = 0;
  for (int r = 0; r < TOP8; ++r) {
    u64 lmax = 0;
#pragma unroll
    for (int s = 0; s < NSLOT; ++s) if (k[s] > lmax) lmax = k[s];
    u32 mhi = (u32)(lmax >> 32), mlo = (u32)lmax;
    DPPMAX(0x111); DPPMAX(0x112); DPPMAX(0x114); DPPMAX(0x118); DPPMAX(0x142); DPPMAX(0x143);
    u32 ghi = (u32)__builtin_amdgcn_readlane((int)mhi, 63);
    u32 glo = (u32)__builtin_amdgcn_readlane((int)mlo, 63);
    u64 g = ((u64)ghi << 32) | (u64)glo;
    if (lane == r) out = g;
#pragma unroll
    for (int s = 0; s < NSLOT; ++s) if (k[s] == g) k[s] = 0;   // keys unique per row
  }
  if (lane < TOP8) top8g[(size_t)row * TOP8 + lane] = out;
}

// 16-way register select, static indices only (no scratch)
__device__ __forceinline__ u64 sel16(const u64* t8, int ri) {
  u64 a0 = (ri & 1) ? t8[1]  : t8[0];
  u64 a1 = (ri & 1) ? t8[3]  : t8[2];
  u64 a2 = (ri & 1) ? t8[5]  : t8[4];
  u64 a3 = (ri & 1) ? t8[7]  : t8[6];
  u64 a4 = (ri & 1) ? t8[9]  : t8[8];
  u64 a5 = (ri & 1) ? t8[11] : t8[10];
  u64 a6 = (ri & 1) ? t8[13] : t8[12];
  u64 a7 = (ri & 1) ? t8[15] : t8[14];
  u64 b0 = (ri & 2) ? a1 : a0;
  u64 b1 = (ri & 2) ? a3 : a2;
  u64 b2 = (ri & 2) ? a5 : a4;
  u64 b3 = (ri & 2) ? a7 : a6;
  u64 c0 = (ri & 4) ? b1 : b0;
  u64 c1 = (ri & 4) ? b3 : b2;
  return (ri & 8) ? c1 : c0;
}

// Kernel B: the serial buggy-JV matcher, 1 wave, register-file staging + bound gate.
// t8 layout: lane l, reg r holds top8 entry (l&7) of row (l>>3)+8r (0-based rows).
// Invariants: visited => owned; v!=0 => owned; ownership frozen during a search.
__global__ __launch_bounds__(64, 1) void match_kernel(const float4* __restrict__ pbox,
                                                      const float4* __restrict__ tboxg,
                                                      const u64* __restrict__ ckey,
                                                      const u64* __restrict__ top8g,
                                                      int* __restrict__ pairs,
                                                      int M, int NROWS) {
  const int lane = threadIdx.x;
  __shared__ u32 s_mask[MASKW];         // only for the rare all-top8-owned fallback
  for (int i = lane; i < MASKW; i += 64) s_mask[i] = 0;
  __syncthreads();

  float4 zf = make_float4(0.f, 0.f, 0.f, 0.f);
  float4 tbA = (lane < NROWS) ? tboxg[lane] : zf;
  float4 tbB = (lane + 64 < NROWS) ? tboxg[lane + 64] : zf;

  u64 t8[16];
#pragma unroll
  for (int r = 0; r < 16; ++r) {
    int rw = (lane >> 3) + (r << 3);
    t8[r] = (rw < NROWS) ? top8g[(size_t)rw * TOP8 + (lane & 7)] : 0ull;
  }

  double u_a = 0.0, u_b = 0.0;          // u[lane+1], u[lane+65]
  int f_a = 0, f_b = 0;                 // in-chain flags
  int oc0 = -1, orow0 = 0, ovis0 = 0; double ov0 = 0.0; float4 ob0 = zf;
  int oc1 = -1, orow1 = 0, ovis1 = 0; double ov1 = 0.0; float4 ob1 = zf;
  int nown = 0;
  double vmax = 0.0;                    // uniform upper bound on all owned v
  bool inchain = false;

  u64 head_key = 0;
  float4 hbox = zf;
  int row = 1, i0 = 1;
  double u_i0 = 0.0;

  // stage head for row rr (1-based) from registers; rare global fallback via s_mask
  auto stage_reg = [&](int rr) -> u64 {
    int rr0 = rr - 1;
    u64 sel = sel16(t8, rr0 >> 3);
    int g = rr0 & 7;
    if ((lane >> 3) != g) sel = 0;
    u32 mhi = (u32)(sel >> 32), mlo = (u32)sel;
    DPPMAX(0x111); DPPMAX(0x112); DPPMAX(0x114);       // group max at lane g*8+7
    u32 ghi = (u32)__builtin_amdgcn_readlane((int)mhi, (g << 3) + 7);
    u32 glo = (u32)__builtin_amdgcn_readlane((int)mlo, (g << 3) + 7);
    u64 hk = ((u64)ghi << 32) | (u64)glo;
    if (hk == 0) {                                     // all top-8 owned: full-pool scan
      asm volatile("s_waitcnt lgkmcnt(0)" ::: "memory");
      const u64* kp = ckey + (size_t)rr0 * CAND;
      u64 lmax = 0;
#pragma unroll
      for (int s = 0; s < NSLOT; ++s) {
        u64 k = kp[(s << 6) + lane];
        if (k) {
          u32 cw = 0xFFFFFFFFu - (u32)k;
          if ((s_mask[cw >> 5] >> (cw & 31u)) & 1u) k = 0;
          if (k > lmax) lmax = k;
        }
      }
      u32 mh2 = (u32)(lmax >> 32), ml2 = (u32)lmax;
      { u32 mhi = mh2, mlo = ml2;
        DPPMAX(0x111); DPPMAX(0x112); DPPMAX(0x114); DPPMAX(0x118); DPPMAX(0x142); DPPMAX(0x143);
        mh2 = (u32)__builtin_amdgcn_readlane((int)mhi, 63);
        ml2 = (u32)__builtin_amdgcn_readlane((int)mlo, 63); }
      hk = ((u64)mh2 << 32) | (u64)ml2;
    }
    return hk;
  };

  head_key = stage_reg(1);
  hbox = pbox[0xFFFFFFFFu - (u32)head_key];
  f_a = (lane == 0); f_b = 0;
  u_i0 = 0.0;

  bool fin = false;
  for (int guard = 0; guard < 5000 && !fin; ++guard) {
    if (head_key == 0) break;           // unreachable safety

    float hio = __uint_as_float((u32)(head_key >> 32));
    int hcol = (int)(0xFFFFFFFFu - (u32)head_key);
    double curh = (-(double)hio) - u_i0;               // exact reference f64 op order

    // ---- gate: owned costs >= fl(fl(-1-u_i0)-vmax); strict > means head wins ----
    bool fast;
    if (nown == 0) fast = true;
    else {
      double bound = (-1.0 - u_i0) - vmax;
      fast = (bound > curh);
    }

    double delta;
    bool do_aug;
    int jc = hcol;

    if (fast) {
      delta = curh;                                    // == reference minv (head is argmin)
      do_aug = true;
    } else {
      // ---- full round-9 slow path: owned eval (inline iou) + DPP min + compare ----
      int li = (i0 - 1) & 63, hb2 = (i0 - 1) >> 6;
      float tx = __int_as_float(__builtin_amdgcn_readlane(__float_as_int(hb2 ? tbB.x : tbA.x), li));
      float ty = __int_as_float(__builtin_amdgcn_readlane(__float_as_int(hb2 ? tbB.y : tbA.y), li));
      float tz = __int_as_float(__builtin_amdgcn_readlane(__float_as_int(hb2 ? tbB.z : tbA.z), li));
      float tw = __int_as_float(__builtin_amdgcn_readlane(__float_as_int(hb2 ? tbB.w : tbA.w), li));
      float4 tbi = make_float4(tx, ty, tz, tw);
      float ati = (tz - tx) * (tw - ty);

      u32 bhi = 0xFFFFFFFFu, blo = 0xFFFFFFFFu; int bcol = 0x7fffffff; int bsl = 15;
      if (oc0 >= 0 && ovis0 != row) {
        float io2 = iou_f32(ob0, tbi, ati);
        double cur = ((-(double)io2) - u_i0) - ov0;
        u64 mk = map_cost(cur);
        bhi = (u32)(mk >> 32); blo = (u32)mk; bcol = oc0; bsl = 6;
      }
      if (oc1 >= 0 && ovis1 != row) {
        float io2 = iou_f32(ob1, tbi, ati);
        double cur = ((-(double)io2) - u_i0) - ov1;
        u64 mk = map_cost(cur);
        u32 hi = (u32)(mk >> 32), lo = (u32)mk;
        bool t = (hi < bhi) || (hi == bhi && ((lo < blo) || (lo == blo && oc1 < bcol)));
        if (t) { bhi = hi; blo = lo; bcol = oc1; bsl = 7; }
      }
      u32 khi = bhi, klo = blo; int kcol = bcol;
      DPP_STEP(0x111); DPP_STEP(0x112); DPP_STEP(0x114); DPP_STEP(0x118);
      DPP_STEP(0x142); DPP_STEP(0x143);
      u32 rhi = (u32)__builtin_amdgcn_readlane((int)khi, 63);
      u32 rlo = (u32)__builtin_amdgcn_readlane((int)klo, 63);
      int rcol = __builtin_amdgcn_readlane(kcol, 63);

      u64 mh = map_cost(curh);
      u32 hhi = (u32)(mh >> 32), hlo = (u32)mh;
      bool head_wins = (hhi < rhi) || (hhi == rhi && ((hlo < rlo) || (hlo == rlo && hcol < rcol)));
      delta = unmap_cost(head_wins ? mh : (((u64)rhi << 32) | (u64)rlo));
      do_aug = head_wins;

      if (!head_wins) {
        // chain bookkeeping (before per-lane updates below, matching round 9 order:
        // updates use the pre-append used set; the new visited col's v unchanged this iter)
        bool eq = (bhi == rhi) && (blo == rlo) && (bcol == rcol);
        u64 wm = __ballot(eq);
        int L = (int)__ffsll((long long)wm) - 1;
        L = __builtin_amdgcn_readfirstlane(L);
        int s_w = __builtin_amdgcn_readlane(bsl, L);
        int o = __builtin_amdgcn_readlane((s_w == 6) ? orow0 : orow1, L);
        o = __builtin_amdgcn_readfirstlane(o);
        // per-lane u/v updates (pre-append set)
        if (f_a) u_a += delta;
        if (f_b) u_b += delta;
        u_i0 += delta;
        if (oc0 >= 0 && ovis0 == row) ov0 -= delta;
        if (oc1 >= 0 && ovis1 == row) ov1 -= delta;
        if (inchain) vmax = fmax(vmax, vmax - delta);
        inchain = true;
        // mark visited, extend chain
        if (lane == L) { if (s_w == 6) ovis0 = row; else ovis1 = row; }
        int ol = (o - 1) & 63, oh = (o - 1) >> 6;
        if (lane == ol) { if (oh == 0) f_a = 1; else f_b = 1; }
        double uo = oh ? u_b : u_a;
        int uhi2 = __builtin_amdgcn_readlane(__double2hiint(uo), ol);
        int ulo2 = __builtin_amdgcn_readlane(__double2loint(uo), ol);
        u_i0 = __hiloint2double(uhi2, ulo2);
        i0 = o;
        head_key = stage_reg(o);
        hbox = pbox[0xFFFFFFFFu - (u32)head_key];
        continue;
      }
    }

    // ---- augment path (fast or slow head_wins) ----
    if (f_a) u_a += delta;
    if (f_b) u_b += delta;
    if (oc0 >= 0 && ovis0 == row) ov0 -= delta;
    if (oc1 >= 0 && ovis1 == row) ov1 -= delta;
    if (inchain) vmax = fmax(vmax, vmax - delta);

    if (lane == 0) {
      pairs[row - 1] = jc;
      atomicOr(&s_mask[(u32)jc >> 5], 1u << ((u32)jc & 31u));   // fire-and-forget
    }
    {
      u32 cjw = 0xFFFFFFFFu - (u32)jc;
#pragma unroll
      for (int r = 0; r < 16; ++r) if ((u32)t8[r] == cjw) t8[r] = 0;
    }
    {
      int ne = nown, nl = ne & 63, nh = ne >> 6;
      if (lane == nl) {
        if (nh == 0) { oc0 = jc; orow0 = row; ovis0 = 0; ov0 = 0.0; ob0 = hbox; }
        else         { oc1 = jc; orow1 = row; ovis1 = 0; ov1 = 0.0; ob1 = hbox; }
      }
      nown = ne + 1;
    }
    vmax = fmax(vmax, 0.0);
    if (row == NROWS) { fin = true; }
    else {
      ++row; i0 = row; u_i0 = 0.0; inchain = false;
      f_a = (lane == ((row - 1) & 63)) && (((row - 1) >> 6) == 0);
      f_b = (lane == ((row - 1) & 63)) && (((row - 1) >> 6) == 1);
      head_key = stage_reg(row);
      hbox = pbox[0xFFFFFFFFu - (u32)head_key];
    }
  }
}

__global__ __launch_bounds__(256) void loss_kernel(const float4* __restrict__ pbox,
                                                   const float* __restrict__ confs,
                                                   const float4* __restrict__ tbox,
                                                   const int* __restrict__ tlab,
                                                   const int* __restrict__ pairs,
                                                   float* __restrict__ out,
                                                   int NROWS, int C) {
  const int tid = threadIdx.x;
  __shared__ float s_reg[256];
  __shared__ float s_cls[256];
  __shared__ int   s_acc[256];
  float reg = 0.0f, cls = 0.0f; int acc = 0;
  if (tid < NROWS) {
    int pred = pairs[tid];
    float4 pb = pbox[pred];
    float4 tb = tbox[tid];
    float d0 = pb.x - tb.x, d1 = pb.y - tb.y, d2 = pb.z - tb.z, d3 = pb.w - tb.w;
    float a0 = fabsf(d0), a1 = fabsf(d1), a2 = fabsf(d2), a3 = fabsf(d3);
    float s = 0.0f;
    s += (a0 < 1.0f) ? 0.5f * d0 * d0 : a0 - 0.5f;
    s += (a1 < 1.0f) ? 0.5f * d1 * d1 : a1 - 0.5f;
    s += (a2 < 1.0f) ? 0.5f * d2 * d2 : a2 - 0.5f;
    s += (a3 < 1.0f) ? 0.5f * d3 * d3 : a3 - 0.5f;
    reg = s * 0.25f;

    const float* lg = confs + (long long)pred * C;
    float mx = lg[0]; int am = 0;
    for (int k = 1; k < C; ++k) { float x = lg[k]; if (x > mx) { mx = x; am = k; } }
    double se = 0.0;
    for (int k = 0; k < C; ++k) se += exp((double)(lg[k] - mx));
    int lab = tlab[tid];
    double logp = (double)(lg[lab] - mx) - log(se);
    cls = (float)(-logp);
    acc = (am == lab) ? 1 : 0;
  }
  s_reg[tid] = reg; s_cls[tid] = cls; s_acc[tid] = acc;
  __syncthreads();
  for (int s2 = 128; s2 > 0; s2 >>= 1) {
    if (tid < s2) {
      s_reg[tid] += s_reg[tid + s2];
      s_cls[tid] += s_cls[tid + s2];
      s_acc[tid] += s_acc[tid + s2];
    }
    __syncthreads();
  }
  if (tid == 0) {
    out[0] = s_reg[0] + s_cls[0];
    out[1] = (float)s_acc[0];
  }
}

extern "C" void kernel_launch(void* const* d_in, const int* in_sizes, int n_in,
                              void* d_out, int out_size, void* d_ws, size_t ws_size,
                              hipStream_t stream) {
  const float4* pbox  = (const float4*)d_in[0];
  const float*  confs = (const float*)d_in[1];
  const float4* tbox  = (const float4*)d_in[2];
  const int*    tlab  = (const int*)d_in[3];

  int N = in_sizes[0] / 4;          // 100000 predictions (columns)
  int C = in_sizes[1] / N;          // 81 classes
  int NROWS = in_sizes[2] / 4;      // 128 targets (rows), <=128 supported
  int M = N;

  char* w = (char*)d_ws;
  auto alloc = [&](size_t sz) { char* r = w; w += (sz + 255) & ~(size_t)255; return r; };
  u64* ckey  = (u64*)alloc((size_t)NROWS * CAND * sizeof(u64));
  u64* top8g = (u64*)alloc((size_t)NROWS * TOP8 * sizeof(u64));
  int* pairs = (int*)alloc((size_t)(NROWS + 8) * sizeof(int));

  select_kernel<<<dim3(SLICES, NROWS), SEL_THR, 0, stream>>>(pbox, tbox, ckey, M, NROWS);
  top8_kernel<<<NROWS, 64, 0, stream>>>(ckey, top8g, NROWS);
  match_kernel<<<1, 64, 0, stream>>>(pbox, tbox, ckey, top8g, pairs, M, NROWS);
  loss_kernel<<<1, 256, 0, stream>>>(pbox, confs, tbox, tlab, pairs,
                                     (float*)d_out, NROWS, C);
}